// Round 9
// baseline (88.510 us; speedup 1.0000x reference)
//
#include <hip/hip_runtime.h>
#include <utility>
#include <math.h>

// Problem constants (fixed by the reference)
#define BATCH     128
#define IN_DIM    784
#define HIDDEN    100
#define MM        10      // M_MODES
#define NPH       5       // N_PHOT
#define NSTATES   2002    // C(14,5)
#define NCLASSES  10

// ---------------------------------------------------------------------------
// Compile-time state tables, lexicographic = itertools order.
// STATE_TBL: 5 x 4-bit mode digits. RFACT: 1/(256*prod factorial(mult)).
// ---------------------------------------------------------------------------
struct StateTbl { unsigned v[2048]; };
struct RFactTbl { float    v[2048]; };

constexpr StateTbl make_state_tbl() {
    StateTbl t{};
    int idx = 0;
    for (int a = 0; a < MM; ++a)
    for (int b = a; b < MM; ++b)
    for (int c = b; c < MM; ++c)
    for (int d = c; d < MM; ++d)
    for (int e = d; e < MM; ++e) {
        t.v[idx++] = (unsigned)a | ((unsigned)b << 4) | ((unsigned)c << 8) |
                     ((unsigned)d << 12) | ((unsigned)e << 16);
    }
    for (; idx < 2048; ++idx) t.v[idx] = 0;
    return t;
}

constexpr RFactTbl make_rfact_tbl() {
    RFactTbl t{};
    int idx = 0;
    for (int a = 0; a < MM; ++a)
    for (int b = a; b < MM; ++b)
    for (int c = b; c < MM; ++c)
    for (int d = c; d < MM; ++d)
    for (int e = d; e < MM; ++e) {
        int cnt[MM] = {};
        cnt[a]++; cnt[b]++; cnt[c]++; cnt[d]++; cnt[e]++;
        int f = 1;
        for (int m = 0; m < MM; ++m) {
            int kf = 1;
            for (int i = 2; i <= cnt[m]; ++i) kf *= i;
            f *= kf;
        }
        t.v[idx++] = 1.0f / (256.0f * (float)f);
    }
    for (; idx < 2048; ++idx) t.v[idx] = 0.f;
    return t;
}

__device__ const StateTbl STATE_TBL = make_state_tbl();
__device__ const RFactTbl RFACT_TBL = make_rfact_tbl();

// ---------------------------------------------------------------------------
// Glynn formula, Gray-coded over delta_1..delta_4 (delta_0 fixed +1).
// 16 terms, fully unrolled, matrix rows in registers.
// ---------------------------------------------------------------------------
template <int K>   // flip from state K-1 to K, K in [1,16)
__device__ __forceinline__ void glynn_step(
    const float (&mr)[5][5], const float (&mi)[5][5],
    float (&cr)[5], float (&ci)[5], float& accr, float& acci)
{
    constexpr int   bit  = (K & 1) ? 0 : ((K & 2) ? 1 : ((K & 4) ? 2 : 3));
    constexpr int   gray = K ^ (K >> 1);
    constexpr int   row  = bit + 1;                       // delta_row flips
    constexpr float s2   = ((gray >> bit) & 1) ? -2.0f : 2.0f;
    constexpr int   pc   = (gray & 1) + ((gray >> 1) & 1) +
                           ((gray >> 2) & 1) + ((gray >> 3) & 1);
    #pragma unroll
    for (int j = 0; j < 5; ++j) {
        cr[j] = fmaf(s2, mr[row][j], cr[j]);
        ci[j] = fmaf(s2, mi[row][j], ci[j]);
    }
    float pr = cr[0], pi = ci[0];
    #pragma unroll
    for (int j = 1; j < 5; ++j) {
        const float nr = pr * cr[j] - pi * ci[j];
        const float ni = pr * ci[j] + pi * cr[j];
        pr = nr; pi = ni;
    }
    if constexpr ((pc & 1) != 0) { accr -= pr; acci -= pi; }
    else                         { accr += pr; acci += pi; }
}

template <int... Ks>
__device__ __forceinline__ void glynn_run(
    std::integer_sequence<int, Ks...>,
    const float (&mr)[5][5], const float (&mi)[5][5],
    float (&cr)[5], float (&ci)[5], float& accr, float& acci)
{
    (glynn_step<Ks + 1>(mr, mi, cr, ci, accr, acci), ...);
}

// ---------------------------------------------------------------------------
// Fused kernel, full-chip grid: 256 blocks (2 per batch row) x 512 threads.
// R9 change (single variable vs R8): Phase-1 GEMM is now wave-cooperative
// and fully coalesced — wave w handles hidden rows j=w,w+8,...; all 64
// lanes read CONSECUTIVE float4s of W1 row j (1 KB per instr), then a
// shuffle reduce. R8's scheme had each lane reading a different row:
// 64 scattered cache lines per instr, ~200-cyc L2 latency poorly hidden.
// ---------------------------------------------------------------------------
__global__ __launch_bounds__(512)
__attribute__((amdgpu_waves_per_eu(2, 2)))
void qc_fused(
    const float* __restrict__ x, const float* __restrict__ W1,
    const float* __restrict__ b1,
    const float* __restrict__ wl_re, const float* __restrict__ wl_im,
    const float* __restrict__ wr_re, const float* __restrict__ wr_im,
    const float* __restrict__ W2, const float* __restrict__ b2,
    float* __restrict__ out)
{
    __shared__ __align__(16) float xs[IN_DIM];
    __shared__ float  hs[HIDDEN];
    __shared__ float  phc[MM], phs_[MM];
    __shared__ float  plr[50], pli[50];
    __shared__ float2 a2[50];
    __shared__ float  wsum[8][NCLASSES];

    const int b    = blockIdx.x >> 1;
    const int half = blockIdx.x & 1;
    const int tid  = threadIdx.x;
    const int wv   = tid >> 6;
    const int lane = tid & 63;

    // ---- Phase 1: A[b] ----
    if (tid < 196) ((float4*)xs)[tid] = ((const float4*)(x + b * IN_DIM))[tid];
    __syncthreads();

    // Coalesced GEMM: wave w -> rows j = w, w+8, ... (13 or 12 rows/wave).
    // Lane l reads float4 chunk (it*64+l) of W1 row j: contiguous 1 KB/instr.
    #pragma unroll 1
    for (int j = wv; j < HIDDEN; j += 8) {
        const float4* wrow = (const float4*)(W1 + j * IN_DIM);
        float4 a4 = make_float4(0.f, 0.f, 0.f, 0.f);
        #pragma unroll
        for (int it = 0; it < 3; ++it) {
            const int c4 = (it << 6) + lane;              // 0..191
            const float4 w4 = wrow[c4];
            const float4 x4 = ((const float4*)xs)[c4];
            a4.x = fmaf(w4.x, x4.x, a4.x); a4.y = fmaf(w4.y, x4.y, a4.y);
            a4.z = fmaf(w4.z, x4.z, a4.z); a4.w = fmaf(w4.w, x4.w, a4.w);
        }
        if (lane < 4) {                                    // chunks 192..195
            const int c4 = 192 + lane;
            const float4 w4 = wrow[c4];
            const float4 x4 = ((const float4*)xs)[c4];
            a4.x = fmaf(w4.x, x4.x, a4.x); a4.y = fmaf(w4.y, x4.y, a4.y);
            a4.z = fmaf(w4.z, x4.z, a4.z); a4.w = fmaf(w4.w, x4.w, a4.w);
        }
        float a = (a4.x + a4.y) + (a4.z + a4.w);
        #pragma unroll
        for (int off = 32; off > 0; off >>= 1) a += __shfl_down(a, off, 64);
        if (lane == 0) {
            const float t = a + b1[j];
            hs[j] = 1.0f / (1.0f + expf(-t));
        }
    }
    __syncthreads();

    if (tid < MM) {
        float th = 0.f;
        #pragma unroll
        for (int g = 0; g < MM; ++g) th += hs[g * MM + tid];
        float sv, cv;
        sincosf(th, &sv, &cv);
        phc[tid] = cv; phs_[tid] = sv;
    }
    __syncthreads();

    if (tid < 50) {   // PL[q][c] = phase[q] * WL[q][2c]
        const int q = tid / 5, c = tid % 5;
        const float lr = wl_re[q * MM + 2 * c], li = wl_im[q * MM + 2 * c];
        plr[tid] = phc[q] * lr - phs_[q] * li;
        pli[tid] = phc[q] * li + phs_[q] * lr;
    }
    __syncthreads();

    if (tid < 50) {   // A[p][c] = sum_q WR[p][q] * PL[q][c]
        const int p = tid / 5, c = tid % 5;
        float ar = 0.f, ai = 0.f;
        #pragma unroll
        for (int q = 0; q < MM; ++q) {
            const float rr = wr_re[p * MM + q], ri = wr_im[p * MM + q];
            const float br = plr[q * 5 + c],    bi = pli[q * 5 + c];
            ar += rr * br - ri * bi;
            ai += rr * bi + ri * br;
        }
        a2[tid] = make_float2(ar, ai);
    }
    __syncthreads();

    // ---- Phase 2: this block's half of the states ----
    const int sbase = half * 1001;
    const int send  = sbase + 1001;          // 2002 for half==1

    float cls[NCLASSES] = {0,0,0,0,0,0,0,0,0,0};

    #pragma unroll 1
    for (int t = 0; t < 2; ++t) {
        const int s = sbase + (t << 9) + tid;
        if (s < send) {
            const unsigned w = STATE_TBL.v[s];   // coalesced dword load

            // gather 5x5 complex submatrix into registers (rows = state modes)
            float mr[5][5], mi[5][5];
            #pragma unroll
            for (int n = 0; n < 5; ++n) {
                const int base = ((w >> (4 * n)) & 15) * 5;
                #pragma unroll
                for (int j = 0; j < 5; ++j) {
                    const float2 e = a2[base + j];
                    mr[n][j] = e.x; mi[n][j] = e.y;
                }
            }

            // init: all deltas +1 -> colsums = sum of rows, first term +prod
            float cr[5], ci[5];
            #pragma unroll
            for (int j = 0; j < 5; ++j) {
                cr[j] = ((mr[0][j] + mr[1][j]) + (mr[2][j] + mr[3][j])) + mr[4][j];
                ci[j] = ((mi[0][j] + mi[1][j]) + (mi[2][j] + mi[3][j])) + mi[4][j];
            }
            float accr, acci;
            {
                float pr = cr[0], pi = ci[0];
                #pragma unroll
                for (int j = 1; j < 5; ++j) {
                    const float nr = pr * cr[j] - pi * ci[j];
                    const float ni = pr * ci[j] + pi * cr[j];
                    pr = nr; pi = ni;
                }
                accr = pr; acci = pi;
            }
            glynn_run(std::make_integer_sequence<int, 15>{}, mr, mi,
                      cr, ci, accr, acci);

            // perm = acc/16 -> |perm|^2/fact = (accr^2+acci^2)*1/(256*fact)
            const float prob = (accr * accr + acci * acci) * RFACT_TBL.v[s];

            #pragma unroll
            for (int c = 0; c < NCLASSES; ++c)
                cls[c] = fmaf(prob, W2[c * NSTATES + s], cls[c]);
        }
    }

    // ---- Phase 3: reduce 8 waves -> atomicAdd partials ----
    #pragma unroll
    for (int c = 0; c < NCLASSES; ++c) {
        float v = cls[c];
        #pragma unroll
        for (int off = 32; off > 0; off >>= 1) v += __shfl_down(v, off, 64);
        if (lane == 0) wsum[wv][c] = v;
    }
    __syncthreads();
    if (tid < NCLASSES) {
        float t = 0.f;
        #pragma unroll
        for (int w8 = 0; w8 < 8; ++w8) t += wsum[w8][tid];
        if (half == 0) t += b2[tid];          // bias folded into chunk 0
        atomicAdd(out + b * NCLASSES + tid, t);
    }
}

// ---------------------------------------------------------------------------
extern "C" void kernel_launch(void* const* d_in, const int* in_sizes, int n_in,
                              void* d_out, int out_size, void* d_ws, size_t ws_size,
                              hipStream_t stream)
{
    const float* x     = (const float*)d_in[0];
    const float* W1    = (const float*)d_in[1];
    const float* b1    = (const float*)d_in[2];
    const float* wl_re = (const float*)d_in[3];
    const float* wl_im = (const float*)d_in[4];
    const float* wr_re = (const float*)d_in[5];
    const float* wr_im = (const float*)d_in[6];
    const float* W2    = (const float*)d_in[7];
    const float* b2    = (const float*)d_in[8];
    float*       out   = (float*)d_out;

    qc_fused<<<BATCH * 2, 512, 0, stream>>>(x, W1, b1, wl_re, wl_im,
                                            wr_re, wr_im, W2, b2, out);
}

// Round 10
// 83.619 us; speedup vs baseline: 1.0585x; 1.0585x over previous
//
#include <hip/hip_runtime.h>
#include <utility>
#include <math.h>

// Problem constants (fixed by the reference)
#define BATCH     128
#define IN_DIM    784
#define HIDDEN    100
#define MM        10      // M_MODES
#define NPH       5       // N_PHOT
#define NSTATES   2002    // C(14,5)
#define NCLASSES  10

// ---------------------------------------------------------------------------
// Compile-time state tables, lexicographic = itertools order.
// STATE_TBL: 5 x 4-bit mode digits. RFACT: 1/(256*prod factorial(mult)).
// ---------------------------------------------------------------------------
struct StateTbl { unsigned v[2048]; };
struct RFactTbl { float    v[2048]; };

constexpr StateTbl make_state_tbl() {
    StateTbl t{};
    int idx = 0;
    for (int a = 0; a < MM; ++a)
    for (int b = a; b < MM; ++b)
    for (int c = b; c < MM; ++c)
    for (int d = c; d < MM; ++d)
    for (int e = d; e < MM; ++e) {
        t.v[idx++] = (unsigned)a | ((unsigned)b << 4) | ((unsigned)c << 8) |
                     ((unsigned)d << 12) | ((unsigned)e << 16);
    }
    for (; idx < 2048; ++idx) t.v[idx] = 0;
    return t;
}

constexpr RFactTbl make_rfact_tbl() {
    RFactTbl t{};
    int idx = 0;
    for (int a = 0; a < MM; ++a)
    for (int b = a; b < MM; ++b)
    for (int c = b; c < MM; ++c)
    for (int d = c; d < MM; ++d)
    for (int e = d; e < MM; ++e) {
        int cnt[MM] = {};
        cnt[a]++; cnt[b]++; cnt[c]++; cnt[d]++; cnt[e]++;
        int f = 1;
        for (int m = 0; m < MM; ++m) {
            int kf = 1;
            for (int i = 2; i <= cnt[m]; ++i) kf *= i;
            f *= kf;
        }
        t.v[idx++] = 1.0f / (256.0f * (float)f);
    }
    for (; idx < 2048; ++idx) t.v[idx] = 0.f;
    return t;
}

__device__ const StateTbl STATE_TBL = make_state_tbl();
__device__ const RFactTbl RFACT_TBL = make_rfact_tbl();

// ---------------------------------------------------------------------------
// Glynn formula, Gray-coded over delta_1..delta_4 (delta_0 fixed +1).
// 16 terms, fully unrolled, matrix rows in registers.
// ---------------------------------------------------------------------------
template <int K>   // flip from state K-1 to K, K in [1,16)
__device__ __forceinline__ void glynn_step(
    const float (&mr)[5][5], const float (&mi)[5][5],
    float (&cr)[5], float (&ci)[5], float& accr, float& acci)
{
    constexpr int   bit  = (K & 1) ? 0 : ((K & 2) ? 1 : ((K & 4) ? 2 : 3));
    constexpr int   gray = K ^ (K >> 1);
    constexpr int   row  = bit + 1;                       // delta_row flips
    constexpr float s2   = ((gray >> bit) & 1) ? -2.0f : 2.0f;
    constexpr int   pc   = (gray & 1) + ((gray >> 1) & 1) +
                           ((gray >> 2) & 1) + ((gray >> 3) & 1);
    #pragma unroll
    for (int j = 0; j < 5; ++j) {
        cr[j] = fmaf(s2, mr[row][j], cr[j]);
        ci[j] = fmaf(s2, mi[row][j], ci[j]);
    }
    float pr = cr[0], pi = ci[0];
    #pragma unroll
    for (int j = 1; j < 5; ++j) {
        const float nr = pr * cr[j] - pi * ci[j];
        const float ni = pr * ci[j] + pi * cr[j];
        pr = nr; pi = ni;
    }
    if constexpr ((pc & 1) != 0) { accr -= pr; acci -= pi; }
    else                         { accr += pr; acci += pi; }
}

template <int... Ks>
__device__ __forceinline__ void glynn_run(
    std::integer_sequence<int, Ks...>,
    const float (&mr)[5][5], const float (&mi)[5][5],
    float (&cr)[5], float (&ci)[5], float& accr, float& acci)
{
    (glynn_step<Ks + 1>(mr, mi, cr, ci, accr, acci), ...);
}

// ---------------------------------------------------------------------------
// Stage A: one block per batch row (128 x 512). R8's proven scattered GEMM
// (4 threads/row, float4 x 49 — empirically beats wave-cooperative, R9).
// Writes A[b] (float2 x 50) to ws; seeds out[b][:] = b2 (atomic base).
// W1 is read ONCE per batch row here (R8's fused version read it 2x).
// ---------------------------------------------------------------------------
__global__ __launch_bounds__(512) void qc_stageA(
    const float* __restrict__ x, const float* __restrict__ W1,
    const float* __restrict__ b1,
    const float* __restrict__ wl_re, const float* __restrict__ wl_im,
    const float* __restrict__ wr_re, const float* __restrict__ wr_im,
    const float* __restrict__ b2,
    float2* __restrict__ A_ws, float* __restrict__ out)
{
    __shared__ __align__(16) float xs[IN_DIM];
    __shared__ float part[400];
    __shared__ float hs[HIDDEN];
    __shared__ float phc[MM], phs_[MM];
    __shared__ float plr[50], pli[50];

    const int b   = blockIdx.x;
    const int tid = threadIdx.x;

    if (tid < 196) ((float4*)xs)[tid] = ((const float4*)(x + b * IN_DIM))[tid];
    if (tid < NCLASSES) out[b * NCLASSES + tid] = b2[tid];   // atomic base
    __syncthreads();

    // GEMM: 4 threads per hidden row, 196 elems each (float4 x 49)
    if (tid < 400) {
        const int j = tid >> 2, q = tid & 3;
        const float* wrow = W1 + j * IN_DIM + q * 196;
        const float* xr   = xs + q * 196;
        float4 acc = make_float4(0.f, 0.f, 0.f, 0.f);
        #pragma unroll 7
        for (int i = 0; i < 196; i += 4) {
            const float4 w  = *(const float4*)(wrow + i);
            const float4 xv = *(const float4*)(xr + i);
            acc.x = fmaf(w.x, xv.x, acc.x); acc.y = fmaf(w.y, xv.y, acc.y);
            acc.z = fmaf(w.z, xv.z, acc.z); acc.w = fmaf(w.w, xv.w, acc.w);
        }
        part[tid] = (acc.x + acc.y) + (acc.z + acc.w);
    }
    __syncthreads();

    if (tid < HIDDEN) {
        const float* p = part + 4 * tid;
        const float t = (p[0] + p[1]) + (p[2] + p[3]) + b1[tid];
        hs[tid] = 1.0f / (1.0f + expf(-t));
    }
    __syncthreads();

    if (tid < MM) {
        float th = 0.f;
        #pragma unroll
        for (int g = 0; g < MM; ++g) th += hs[g * MM + tid];
        float sv, cv;
        sincosf(th, &sv, &cv);
        phc[tid] = cv; phs_[tid] = sv;
    }
    __syncthreads();

    if (tid < 50) {   // PL[q][c] = phase[q] * WL[q][2c]
        const int q = tid / 5, c = tid % 5;
        const float lr = wl_re[q * MM + 2 * c], li = wl_im[q * MM + 2 * c];
        plr[tid] = phc[q] * lr - phs_[q] * li;
        pli[tid] = phc[q] * li + phs_[q] * lr;
    }
    __syncthreads();

    if (tid < 50) {   // A[p][c] = sum_q WR[p][q] * PL[q][c]
        const int p = tid / 5, c = tid % 5;
        float ar = 0.f, ai = 0.f;
        #pragma unroll
        for (int q = 0; q < MM; ++q) {
            const float rr = wr_re[p * MM + q], ri = wr_im[p * MM + q];
            const float br = plr[q * 5 + c],    bi = pli[q * 5 + c];
            ar += rr * br - ri * bi;
            ai += rr * bi + ri * br;
        }
        A_ws[b * 50 + tid] = make_float2(ar, ai);
    }
}

// ---------------------------------------------------------------------------
// Stage B: 512 blocks (4 per batch row) x 512 threads — 1 state per thread,
// 2 blocks/CU co-resident. waves_per_eu(4,4): min=max=4 -> 128-VGPR budget
// AND no allocator incentive to compress below it (the R6 52-reg/LDS-reread
// pathology came from an open-ended max). Live set ~70 -> register Glynn.
// Epilogue: probs->LDS, wave w reduces classes {w, w+8} with coalesced W2
// reads, 4 atomicAdds per output element (base = b2 from stage A).
// ---------------------------------------------------------------------------
__global__ __launch_bounds__(512)
__attribute__((amdgpu_waves_per_eu(4, 4)))
void qc_stageB(
    const float2* __restrict__ A_ws, const float* __restrict__ W2,
    float* __restrict__ out)
{
    __shared__ float2 a2[50];
    __shared__ float  probs[512];

    const int tid     = threadIdx.x;
    const int b       = blockIdx.x >> 2;
    const int quarter = blockIdx.x & 3;
    const int sbase   = quarter << 9;          // 0,512,1024,1536
    const int s       = sbase + tid;

    if (tid < 50) a2[tid] = A_ws[b * 50 + tid];
    __syncthreads();

    float prob = 0.f;
    if (s < NSTATES) {
        const unsigned w = STATE_TBL.v[s];     // coalesced dword load

        // gather 5x5 complex submatrix into registers (rows = state modes)
        float mr[5][5], mi[5][5];
        #pragma unroll
        for (int n = 0; n < 5; ++n) {
            const int base = ((w >> (4 * n)) & 15) * 5;
            #pragma unroll
            for (int j = 0; j < 5; ++j) {
                const float2 e = a2[base + j];
                mr[n][j] = e.x; mi[n][j] = e.y;
            }
        }

        // init: all deltas +1 -> colsums = sum of rows, first term +prod
        float cr[5], ci[5];
        #pragma unroll
        for (int j = 0; j < 5; ++j) {
            cr[j] = ((mr[0][j] + mr[1][j]) + (mr[2][j] + mr[3][j])) + mr[4][j];
            ci[j] = ((mi[0][j] + mi[1][j]) + (mi[2][j] + mi[3][j])) + mi[4][j];
        }
        float accr, acci;
        {
            float pr = cr[0], pi = ci[0];
            #pragma unroll
            for (int j = 1; j < 5; ++j) {
                const float nr = pr * cr[j] - pi * ci[j];
                const float ni = pr * ci[j] + pi * cr[j];
                pr = nr; pi = ni;
            }
            accr = pr; acci = pi;
        }
        glynn_run(std::make_integer_sequence<int, 15>{}, mr, mi,
                  cr, ci, accr, acci);

        // perm = acc/16 -> |perm|^2/fact = (accr^2+acci^2)*1/(256*fact)
        prob = (accr * accr + acci * acci) * RFACT_TBL.v[s];
    }
    probs[tid] = prob;
    __syncthreads();

    // wave w reduces classes {w, w+8}: partial dot probs . W2[c][sbase..]
    const int wv   = tid >> 6;
    const int lane = tid & 63;
    #pragma unroll 1
    for (int c = wv; c < NCLASSES; c += 8) {
        const float* w2row = W2 + c * NSTATES + sbase;
        const int    lim   = (sbase + 512 <= NSTATES) ? 512 : (NSTATES - sbase);
        float v = 0.f;
        #pragma unroll
        for (int k = lane; k < 512; k += 64)
            if (k < lim) v = fmaf(probs[k], w2row[k], v);
        #pragma unroll
        for (int off = 32; off > 0; off >>= 1) v += __shfl_down(v, off, 64);
        if (lane == 0) atomicAdd(out + b * NCLASSES + c, v);
    }
}

// ---------------------------------------------------------------------------
extern "C" void kernel_launch(void* const* d_in, const int* in_sizes, int n_in,
                              void* d_out, int out_size, void* d_ws, size_t ws_size,
                              hipStream_t stream)
{
    const float* x     = (const float*)d_in[0];
    const float* W1    = (const float*)d_in[1];
    const float* b1    = (const float*)d_in[2];
    const float* wl_re = (const float*)d_in[3];
    const float* wl_im = (const float*)d_in[4];
    const float* wr_re = (const float*)d_in[5];
    const float* wr_im = (const float*)d_in[6];
    const float* W2    = (const float*)d_in[7];
    const float* b2    = (const float*)d_in[8];
    float*       out   = (float*)d_out;
    float2*      A_ws  = (float2*)d_ws;   // 128*50 float2 = 51.2 KB

    qc_stageA<<<BATCH, 512, 0, stream>>>(x, W1, b1, wl_re, wl_im,
                                         wr_re, wr_im, b2, A_ws, out);
    qc_stageB<<<BATCH * 4, 512, 0, stream>>>(A_ws, W2, out);
}